// Round 1
// baseline (585.077 us; speedup 1.0000x reference)
//
#include <hip/hip_runtime.h>

// ---------------------------------------------------------------------------
// MultiHeadAttentionBlock: B=4, S=2048, D=1024, H=16, DK=64
// Pipeline: cvt weights -> pack mask bits -> Q/K/V proj (bf16 MFMA GEMM)
//           -> flash attention (online softmax) -> output proj (f32 out)
// ---------------------------------------------------------------------------

typedef __bf16  bf16x8 __attribute__((ext_vector_type(8)));
typedef float   f32x4  __attribute__((ext_vector_type(4)));
typedef float   fv4    __attribute__((ext_vector_type(4)));
typedef __attribute__((address_space(3))) char        as3c;
typedef __attribute__((address_space(1))) const char  as1c;

static __device__ __forceinline__ void gload16(const void* g, void* l) {
  __builtin_amdgcn_global_load_lds((as1c*)g, (as3c*)l, 16, 0, 0);
}
static __device__ __forceinline__ f32x4 mfma16(bf16x8 a, bf16x8 b, f32x4 c) {
  return __builtin_amdgcn_mfma_f32_16x16x32_bf16(a, b, c, 0, 0, 0);
}
static __device__ __forceinline__ void st4bf(void* dst, float a, float b, float c, float d) {
  union { __bf16 h[4]; unsigned long long u; } x;
  x.h[0] = (__bf16)a; x.h[1] = (__bf16)b; x.h[2] = (__bf16)c; x.h[3] = (__bf16)d;
  *(unsigned long long*)dst = x.u;
}

// ---- weights f32 -> bf16 (4 x 1M elements, exact grid) ----------------------
__global__ void cvt_w(const float* __restrict__ w0, const float* __restrict__ w1,
                      const float* __restrict__ w2, const float* __restrict__ w3,
                      __bf16* __restrict__ dst) {
  int i = (blockIdx.x * 256 + threadIdx.x) * 4;
  int seg = i >> 20, off = i & 1048575;
  const float* s = seg == 0 ? w0 : seg == 1 ? w1 : seg == 2 ? w2 : w3;
  fv4 v = *(const fv4*)(s + off);
  st4bf(dst + i, v[0], v[1], v[2], v[3]);
}

// ---- mask int32 [2048][2048] -> bit-packed u64 [2048][32] -------------------
__global__ void pack_mask(const int* __restrict__ mask,
                          unsigned long long* __restrict__ out) {
  int wid = threadIdx.x >> 6, lane = threadIdx.x & 63;
  for (int w = blockIdx.x * 4 + wid; w < 2048 * 32; w += gridDim.x * 4) {
    int v = mask[(w >> 5) * 2048 + (w & 31) * 64 + lane];
    unsigned long long bits = __ballot(v != 0);
    if (lane == 0) out[w] = bits;
  }
}

// ---- GEMM  C[M=8192][N=1024] = A[8192][1024] @ W[N][K]^T + bias -------------
// MODE 0: A=f32, out bf16, *0.125 (Q)   MODE 1: A=f32, out bf16 (K)
// MODE 2: A=f32, out bf16 TRANSPOSED to Vt[b*1024+n][2048] (V)
// MODE 3: A=bf16, out f32 (final projection)
template<int MODE>
__global__ __launch_bounds__(256, 2)
void gemm_bt(const void* __restrict__ Ap, const __bf16* __restrict__ Bw,
             const float* __restrict__ bias, void* __restrict__ Cp) {
  __shared__ __align__(16) char lds_a[8192];   // 128 rows x 32 k (bf16)
  __shared__ __align__(16) char lds_b[8192];
  const int t = threadIdx.x;
  const int lane = t & 63, lr = lane & 15, lg = lane >> 4;
  const int wid = t >> 6, wr = wid >> 1, wc = wid & 1;
  const int rowStart = blockIdx.x * 128, colStart = blockIdx.y * 128;

  f32x4 acc[4][4];
#pragma unroll
  for (int m = 0; m < 4; ++m)
#pragma unroll
    for (int n = 0; n < 4; ++n) {
      acc[m][n][0] = 0.f; acc[m][n][1] = 0.f; acc[m][n][2] = 0.f; acc[m][n][3] = 0.f;
    }

  for (int kt = 0; kt < 1024; kt += 32) {
    __syncthreads();
    if constexpr (MODE < 3) {      // reg-staged f32 -> bf16 A tile
      const float* A = (const float*)Ap;
#pragma unroll
      for (int rr = 0; rr < 4; ++rr) {
        int lin = rr * 1024 + t * 4;
        int row = lin >> 5, col = lin & 31;
        fv4 v = *(const fv4*)(A + (rowStart + row) * 1024 + kt + col);
        st4bf(lds_a + lin * 2, v[0], v[1], v[2], v[3]);
      }
    } else {                        // bf16 A tile: direct global->LDS
      const __bf16* A = (const __bf16*)Ap;
#pragma unroll
      for (int rr = 0; rr < 2; ++rr) {
        int lin = rr * 2048 + t * 8;
        int row = lin >> 5, col = lin & 31;
        gload16(A + (rowStart + row) * 1024 + kt + col, lds_a + lin * 2);
      }
    }
#pragma unroll
    for (int rr = 0; rr < 2; ++rr) {
      int lin = rr * 2048 + t * 8;
      int row = lin >> 5, col = lin & 31;
      gload16(Bw + (colStart + row) * 1024 + kt + col, lds_b + lin * 2);
    }
    __syncthreads();

    bf16x8 af[4], bfr[4];
#pragma unroll
    for (int m = 0; m < 4; ++m)
      af[m] = *(const bf16x8*)(lds_a + (wr * 64 + m * 16 + lr) * 64 + lg * 16);
#pragma unroll
    for (int n = 0; n < 4; ++n)
      bfr[n] = *(const bf16x8*)(lds_b + (wc * 64 + n * 16 + lr) * 64 + lg * 16);
#pragma unroll
    for (int m = 0; m < 4; ++m)
#pragma unroll
      for (int n = 0; n < 4; ++n)
        acc[m][n] = mfma16(af[m], bfr[n], acc[m][n]);
  }

  // epilogue: C/D layout row=(lane>>4)*4+r, col=lane&15
#pragma unroll
  for (int n = 0; n < 4; ++n) {
    int col = colStart + wc * 64 + n * 16 + lr;
    float bv = bias[col];
#pragma unroll
    for (int m = 0; m < 4; ++m) {
      int rowb = rowStart + wr * 64 + m * 16 + lg * 4;
      if constexpr (MODE == 0 || MODE == 1) {
        __bf16* C = (__bf16*)Cp;
#pragma unroll
        for (int r = 0; r < 4; ++r) {
          float val = acc[m][n][r] + bv;
          if constexpr (MODE == 0) val *= 0.125f;   // fold 1/sqrt(dk)
          C[(rowb + r) * 1024 + col] = (__bf16)val;
        }
      } else if constexpr (MODE == 2) {
        __bf16* C = (__bf16*)Cp;                     // Vt[b*1024+n][2048]
        int bb = rowb >> 11, s = rowb & 2047;        // rows are consecutive s
        st4bf(C + ((bb << 10) + col) * 2048 + s,
              acc[m][n][0] + bv, acc[m][n][1] + bv,
              acc[m][n][2] + bv, acc[m][n][3] + bv);
      } else {
        float* C = (float*)Cp;
#pragma unroll
        for (int r = 0; r < 4; ++r)
          C[(rowb + r) * 1024 + col] = acc[m][n][r] + bv;
      }
    }
  }
}

// ---- flash attention --------------------------------------------------------
// grid (16 qblocks, 64 bh), 256 thr. QBLK=128 (wave owns 32 q rows), KBLK=64.
__global__ __launch_bounds__(256, 2)
void attn_fwd(const __bf16* __restrict__ Qp, const __bf16* __restrict__ Kp,
              const __bf16* __restrict__ Vt, const unsigned long long* __restrict__ Mb,
              __bf16* __restrict__ Xb) {
  __shared__ __align__(16) char lds_k[8192];      // [64 k][64 d] bf16, XOR-swizzled
  __shared__ __align__(16) char lds_v[8192];      // [64 d][64 k] bf16, XOR-swizzled
  __shared__ __align__(16) char lds_p[4 * 2304];  // per-wave [16][72] bf16 (pad->2-way)
  const int t = threadIdx.x;
  const int lane = t & 63, lr = lane & 15, lg = lane >> 4;
  const int wid = t >> 6;
  const int qblk = blockIdx.x, bh = blockIdx.y;
  const int b = bh >> 4, h = bh & 15;
  const int qbase = qblk * 128 + wid * 32;

  // Q fragments live in registers for the whole kernel (pre-scaled by 1/8)
  bf16x8 qf[2][2];
#pragma unroll
  for (int qt = 0; qt < 2; ++qt)
#pragma unroll
    for (int c = 0; c < 2; ++c)
      qf[qt][c] = *(const bf16x8*)(Qp + (b * 2048 + qbase + qt * 16 + lr) * 1024 +
                                   h * 64 + c * 32 + lg * 8);

  f32x4 xacc[2][4];
  float m_r[2][4], l_r[2][4];
#pragma unroll
  for (int qt = 0; qt < 2; ++qt) {
#pragma unroll
    for (int dt = 0; dt < 4; ++dt) {
      xacc[qt][dt][0] = 0.f; xacc[qt][dt][1] = 0.f;
      xacc[qt][dt][2] = 0.f; xacc[qt][dt][3] = 0.f;
    }
#pragma unroll
    for (int r = 0; r < 4; ++r) { m_r[qt][r] = -__builtin_inff(); l_r[qt][r] = 0.f; }
  }
  char* pbase = lds_p + wid * 2304;

  for (int k0 = 0; k0 < 2048; k0 += 64) {
    __syncthreads();
    // stage K and Vt tiles; LDS linear dest, swizzle folded into global source
#pragma unroll
    for (int rr = 0; rr < 2; ++rr) {
      int o = rr * 4096 + t * 16;
      int row = o >> 7, cb = o & 127;
      int cbs = cb ^ ((row & 7) << 4);
      gload16(Kp + (b * 2048 + k0 + row) * 1024 + h * 64 + (cbs >> 1), lds_k + o);
      gload16(Vt + (bh * 64 + row) * 2048 + k0 + (cbs >> 1), lds_v + o);
    }
    __syncthreads();

#pragma unroll
    for (int qt = 0; qt < 2; ++qt) {
      // ---- scores S = (Q/8) K^T over d=64
      f32x4 sc[4];
#pragma unroll
      for (int ktile = 0; ktile < 4; ++ktile) {
        f32x4 s; s[0] = 0.f; s[1] = 0.f; s[2] = 0.f; s[3] = 0.f;
#pragma unroll
        for (int c = 0; c < 2; ++c) {
          int krow = ktile * 16 + lr;
          int kb = (krow << 7) + (((c << 6) + (lg << 4)) ^ ((krow & 7) << 4));
          bf16x8 kf = *(const bf16x8*)(lds_k + kb);
          s = mfma16(qf[qt][c], kf, s);
        }
        sc[ktile] = s;
      }
      // ---- mask (bit-packed, one u64 per row per k-block)
      unsigned long long mw[4];
#pragma unroll
      for (int r = 0; r < 4; ++r)
        mw[r] = Mb[(qbase + qt * 16 + lg * 4 + r) * 32 + (k0 >> 6)];
      float rm[4] = {-1e30f, -1e30f, -1e30f, -1e30f};
#pragma unroll
      for (int ktile = 0; ktile < 4; ++ktile)
#pragma unroll
        for (int r = 0; r < 4; ++r) {
          bool keep = (mw[r] >> (ktile * 16 + lr)) & 1ull;
          float sv = keep ? sc[ktile][r] : -1e9f;
          sc[ktile][r] = sv;
          rm[r] = fmaxf(rm[r], sv);
        }
      // ---- wave-parallel row-max / row-sum (16-lane groups)
#pragma unroll
      for (int mk = 1; mk < 16; mk <<= 1)
#pragma unroll
        for (int r = 0; r < 4; ++r)
          rm[r] = fmaxf(rm[r], __shfl_xor(rm[r], mk));
      float corr[4], rs[4];
#pragma unroll
      for (int r = 0; r < 4; ++r) {
        float mn = fmaxf(m_r[qt][r], rm[r]);
        corr[r] = __expf(m_r[qt][r] - mn);
        m_r[qt][r] = mn;
        rs[r] = 0.f;
      }
#pragma unroll
      for (int ktile = 0; ktile < 4; ++ktile)
#pragma unroll
        for (int r = 0; r < 4; ++r) {
          float p = __expf(sc[ktile][r] - m_r[qt][r]);
          rs[r] += p;
          *(__bf16*)(pbase + (lg * 4 + r) * 144 + (ktile * 16 + lr) * 2) = (__bf16)p;
        }
#pragma unroll
      for (int mk = 1; mk < 16; mk <<= 1)
#pragma unroll
        for (int r = 0; r < 4; ++r)
          rs[r] += __shfl_xor(rs[r], mk);
#pragma unroll
      for (int r = 0; r < 4; ++r)
        l_r[qt][r] = l_r[qt][r] * corr[r] + rs[r];
#pragma unroll
      for (int dt = 0; dt < 4; ++dt)
#pragma unroll
        for (int r = 0; r < 4; ++r)
          xacc[qt][dt][r] *= corr[r];
      // ---- PV: x += P Vt^T  (wave-private P tile, no barrier needed)
#pragma unroll
      for (int kc = 0; kc < 2; ++kc) {
        bf16x8 pf = *(const bf16x8*)(pbase + lr * 144 + kc * 64 + lg * 16);
#pragma unroll
        for (int dt = 0; dt < 4; ++dt) {
          int vrow = dt * 16 + lr;
          int vb = (vrow << 7) + (((kc << 6) + (lg << 4)) ^ ((vrow & 7) << 4));
          bf16x8 vf = *(const bf16x8*)(lds_v + vb);
          xacc[qt][dt] = mfma16(pf, vf, xacc[qt][dt]);
        }
      }
    }
  }

  // ---- finalize: x / l, store bf16 to Xb[b*2048+s][h*64+d]
#pragma unroll
  for (int qt = 0; qt < 2; ++qt)
#pragma unroll
    for (int r = 0; r < 4; ++r) {
      float inv = 1.f / l_r[qt][r];
      int rowq = qbase + qt * 16 + lg * 4 + r;
#pragma unroll
      for (int dt = 0; dt < 4; ++dt)
        Xb[(b * 2048 + rowq) * 1024 + h * 64 + dt * 16 + lr] =
            (__bf16)(xacc[qt][dt][r] * inv);
    }
}

// ---------------------------------------------------------------------------
extern "C" void kernel_launch(void* const* d_in, const int* in_sizes, int n_in,
                              void* d_out, int out_size, void* d_ws, size_t ws_size,
                              hipStream_t stream) {
  const float* q    = (const float*)d_in[0];
  const float* k    = (const float*)d_in[1];
  const float* v    = (const float*)d_in[2];
  const int*   mask = (const int*)d_in[3];
  const float* wq   = (const float*)d_in[4];
  const float* bq   = (const float*)d_in[5];
  const float* wk   = (const float*)d_in[6];
  const float* bk   = (const float*)d_in[7];
  const float* wv   = (const float*)d_in[8];
  const float* bv   = (const float*)d_in[9];
  const float* wo   = (const float*)d_in[10];
  const float* bo   = (const float*)d_in[11];

  char* ws = (char*)d_ws;
  // layout (bytes): Wb 8MB | Qp 16MB | Kp 16MB | Vt 16MB | Xb 16MB | Mb 0.5MB
  __bf16* Wb  = (__bf16*)(ws);
  __bf16* Qp  = (__bf16*)(ws + (size_t)(8u  << 20));
  __bf16* Kp  = (__bf16*)(ws + (size_t)(24u << 20));
  __bf16* Vtb = (__bf16*)(ws + (size_t)(40u << 20));
  __bf16* Xb  = (__bf16*)(ws + (size_t)(56u << 20));
  unsigned long long* Mb = (unsigned long long*)(ws + (size_t)(72u << 20));

  cvt_w<<<4096, 256, 0, stream>>>(wq, wk, wv, wo, Wb);
  pack_mask<<<512, 256, 0, stream>>>(mask, Mb);
  gemm_bt<0><<<dim3(64, 8), 256, 0, stream>>>(q, Wb,                 bq, Qp);
  gemm_bt<1><<<dim3(64, 8), 256, 0, stream>>>(k, Wb + (1u << 20),    bk, Kp);
  gemm_bt<2><<<dim3(64, 8), 256, 0, stream>>>(v, Wb + (2u << 20),    bv, Vtb);
  attn_fwd<<<dim3(16, 64), 256, 0, stream>>>(Qp, Kp, Vtb, Mb, Xb);
  gemm_bt<3><<<dim3(64, 8), 256, 0, stream>>>(Xb, Wb + (3u << 20),   bo, (float*)d_out);
}

// Round 2
// 445.474 us; speedup vs baseline: 1.3134x; 1.3134x over previous
//
#include <hip/hip_runtime.h>

// ---------------------------------------------------------------------------
// MultiHeadAttentionBlock: B=4, S=2048, D=1024, H=16, DK=64
// cvt weights -> pack mask bits -> Q/K/V proj (bf16 MFMA GEMM)
// -> flash attention (32x32 swapped-operand, in-register softmax) -> out proj
// ---------------------------------------------------------------------------

typedef __bf16  bf16x8 __attribute__((ext_vector_type(8)));
typedef float   f32x4  __attribute__((ext_vector_type(4)));
typedef float   f32x16 __attribute__((ext_vector_type(16)));
typedef float   fv4    __attribute__((ext_vector_type(4)));
typedef unsigned int uint;
typedef __attribute__((address_space(3))) char        as3c;
typedef __attribute__((address_space(1))) const char  as1c;

static __device__ __forceinline__ void gload16(const void* g, void* l) {
  __builtin_amdgcn_global_load_lds((as1c*)g, (as3c*)l, 16, 0, 0);
}
static __device__ __forceinline__ f32x4 mfma16(bf16x8 a, bf16x8 b, f32x4 c) {
  return __builtin_amdgcn_mfma_f32_16x16x32_bf16(a, b, c, 0, 0, 0);
}
static __device__ __forceinline__ f32x16 mfma32(bf16x8 a, bf16x8 b, f32x16 c) {
  return __builtin_amdgcn_mfma_f32_32x32x16_bf16(a, b, c, 0, 0, 0);
}
static __device__ __forceinline__ void st4bf(void* dst, float a, float b, float c, float d) {
  union { __bf16 h[4]; unsigned long long u; } x;
  x.h[0] = (__bf16)a; x.h[1] = (__bf16)b; x.h[2] = (__bf16)c; x.h[3] = (__bf16)d;
  *(unsigned long long*)dst = x.u;
}
static __device__ __forceinline__ uint pk2(float lo, float hi) {
  union { __bf16 h[2]; uint u; } x;
  x.h[0] = (__bf16)lo; x.h[1] = (__bf16)hi; return x.u;
}
static __device__ __forceinline__ f32x16 fzero16() {
  f32x16 z;
#pragma unroll
  for (int i = 0; i < 16; ++i) z[i] = 0.f;
  return z;
}

// ---- weights f32 -> bf16 (4 x 1M elements, exact grid) ----------------------
__global__ void cvt_w(const float* __restrict__ w0, const float* __restrict__ w1,
                      const float* __restrict__ w2, const float* __restrict__ w3,
                      __bf16* __restrict__ dst) {
  int i = (blockIdx.x * 256 + threadIdx.x) * 4;
  int seg = i >> 20, off = i & 1048575;
  const float* s = seg == 0 ? w0 : seg == 1 ? w1 : seg == 2 ? w2 : w3;
  fv4 v = *(const fv4*)(s + off);
  st4bf(dst + i, v[0], v[1], v[2], v[3]);
}

// ---- mask int32 [2048][2048] -> bit-packed u64 [2048][32] -------------------
__global__ void pack_mask(const int* __restrict__ mask,
                          unsigned long long* __restrict__ out) {
  int wid = threadIdx.x >> 6, lane = threadIdx.x & 63;
  for (int w = blockIdx.x * 4 + wid; w < 2048 * 32; w += gridDim.x * 4) {
    int v = mask[(w >> 5) * 2048 + (w & 31) * 64 + lane];
    unsigned long long bits = __ballot(v != 0);
    if (lane == 0) out[w] = bits;
  }
}

// ---- GEMM  C[M=8192][N=1024] = A[8192][1024] @ W[N][K]^T + bias -------------
// MODE 0: A=f32, out bf16, *0.125 (Q)   MODE 1: A=f32, out bf16 (K)
// MODE 2: A=f32, out bf16 TRANSPOSED to Vt[b*1024+n][2048] (V)
// MODE 3: A=bf16, out f32 (final projection)
template<int MODE>
__global__ __launch_bounds__(256, 2)
void gemm_bt(const void* __restrict__ Ap, const __bf16* __restrict__ Bw,
             const float* __restrict__ bias, void* __restrict__ Cp) {
  __shared__ __align__(16) char lds_a[8192];   // 128 rows x 32 k (bf16)
  __shared__ __align__(16) char lds_b[8192];
  const int t = threadIdx.x;
  const int lane = t & 63, lr = lane & 15, lg = lane >> 4;
  const int wid = t >> 6, wr = wid >> 1, wc = wid & 1;
  const int rowStart = blockIdx.x * 128, colStart = blockIdx.y * 128;

  f32x4 acc[4][4];
#pragma unroll
  for (int m = 0; m < 4; ++m)
#pragma unroll
    for (int n = 0; n < 4; ++n) {
      acc[m][n][0] = 0.f; acc[m][n][1] = 0.f; acc[m][n][2] = 0.f; acc[m][n][3] = 0.f;
    }

  for (int kt = 0; kt < 1024; kt += 32) {
    __syncthreads();
    if constexpr (MODE < 3) {      // reg-staged f32 -> bf16 A tile
      const float* A = (const float*)Ap;
#pragma unroll
      for (int rr = 0; rr < 4; ++rr) {
        int lin = rr * 1024 + t * 4;
        int row = lin >> 5, col = lin & 31;
        fv4 v = *(const fv4*)(A + (rowStart + row) * 1024 + kt + col);
        st4bf(lds_a + lin * 2, v[0], v[1], v[2], v[3]);
      }
    } else {                        // bf16 A tile: direct global->LDS
      const __bf16* A = (const __bf16*)Ap;
#pragma unroll
      for (int rr = 0; rr < 2; ++rr) {
        int lin = rr * 2048 + t * 8;
        int row = lin >> 5, col = lin & 31;
        gload16(A + (rowStart + row) * 1024 + kt + col, lds_a + lin * 2);
      }
    }
#pragma unroll
    for (int rr = 0; rr < 2; ++rr) {
      int lin = rr * 2048 + t * 8;
      int row = lin >> 5, col = lin & 31;
      gload16(Bw + (colStart + row) * 1024 + kt + col, lds_b + lin * 2);
    }
    __syncthreads();

    bf16x8 af[4], bfr[4];
#pragma unroll
    for (int m = 0; m < 4; ++m)
      af[m] = *(const bf16x8*)(lds_a + (wr * 64 + m * 16 + lr) * 64 + lg * 16);
#pragma unroll
    for (int n = 0; n < 4; ++n)
      bfr[n] = *(const bf16x8*)(lds_b + (wc * 64 + n * 16 + lr) * 64 + lg * 16);
#pragma unroll
    for (int m = 0; m < 4; ++m)
#pragma unroll
      for (int n = 0; n < 4; ++n)
        acc[m][n] = mfma16(af[m], bfr[n], acc[m][n]);
  }

  // epilogue: C/D layout row=(lane>>4)*4+r, col=lane&15
#pragma unroll
  for (int n = 0; n < 4; ++n) {
    int col = colStart + wc * 64 + n * 16 + lr;
    float bv = bias[col];
#pragma unroll
    for (int m = 0; m < 4; ++m) {
      int rowb = rowStart + wr * 64 + m * 16 + lg * 4;
      if constexpr (MODE == 0 || MODE == 1) {
        __bf16* C = (__bf16*)Cp;
#pragma unroll
        for (int r = 0; r < 4; ++r) {
          float val = acc[m][n][r] + bv;
          if constexpr (MODE == 0) val *= 0.125f;   // fold 1/sqrt(dk)
          C[(rowb + r) * 1024 + col] = (__bf16)val;
        }
      } else if constexpr (MODE == 2) {
        __bf16* C = (__bf16*)Cp;                     // Vt[b*1024+n][2048]
        int bb = rowb >> 11, s = rowb & 2047;        // rows are consecutive s
        st4bf(C + ((bb << 10) + col) * 2048 + s,
              acc[m][n][0] + bv, acc[m][n][1] + bv,
              acc[m][n][2] + bv, acc[m][n][3] + bv);
      } else {
        float* C = (float*)Cp;
#pragma unroll
        for (int r = 0; r < 4; ++r)
          C[(rowb + r) * 1024 + col] = acc[m][n][r] + bv;
      }
    }
  }
}

// ---- flash attention, 32x32 swapped-operand form ----------------------------
// grid (16 qblocks, 64 bh), 256 thr. Wave owns 32 q (q = lane&31), KBLK=64.
// QK^T = mfma(K, Q) -> S[k][q];  PV = mfma(Vt, P) -> X[d][q].
// P reaches the B-operand layout via bf16 packs + v_permlane32_swap (no LDS).
__global__ __launch_bounds__(256, 4)
void attn_fwd(const __bf16* __restrict__ Qp, const __bf16* __restrict__ Kp,
              const __bf16* __restrict__ Vt, const unsigned long long* __restrict__ Mb,
              __bf16* __restrict__ Xb) {
  __shared__ __align__(16) char lds[2][16384];   // [buf][ K:8192 | V:8192 ]
  const int t = threadIdx.x;
  const int lane = t & 63;
  const int l31 = lane & 31, hi = lane >> 5;
  const int wid = t >> 6;
  const int qblk = blockIdx.x, bh = blockIdx.y;
  const int b = bh >> 4, h = bh & 15;
  const int q = qblk * 128 + wid * 32 + l31;     // this lane's q column

  // Q fragments (B operand): row q, d = c*16 + hi*8 + j  (Q pre-scaled by 1/8)
  bf16x8 qf[4];
#pragma unroll
  for (int c = 0; c < 4; ++c)
    qf[c] = *(const bf16x8*)(Qp + (b * 2048 + q) * 1024 + h * 64 + c * 16 + hi * 8);

  f32x16 xacc0 = fzero16(), xacc1 = fzero16();   // X[d][q], d-tiles 0..31 / 32..63
  float m_r = -__builtin_inff(), l_r = 0.f;

  // stage K and Vt tiles; LDS linear dest, XOR swizzle folded into global src
  auto stage = [&](int buf, int k0) {
#pragma unroll
    for (int rr = 0; rr < 2; ++rr) {
      int o = rr * 4096 + t * 16;
      int row = o >> 7, cb = o & 127;
      int cbs = cb ^ ((row & 7) << 4);
      gload16(Kp + (b * 2048 + k0 + row) * 1024 + h * 64 + (cbs >> 1), &lds[buf][o]);
      gload16(Vt + (bh * 64 + row) * 2048 + k0 + (cbs >> 1), &lds[buf][8192 + o]);
    }
  };

  stage(0, 0);
  int cur = 0;
  for (int it = 0; it < 32; ++it) {
    __syncthreads();                 // drains own gload_lds (vmcnt) + barrier
    if (it + 1 < 32) stage(cur ^ 1, (it + 1) * 64);   // overlap with compute

    const char* lk = lds[cur];
    const char* lv = lds[cur] + 8192;

    // ---- scores S[k][q] (2 k-tiles of 32), contraction d=64 in 4 slices
    f32x16 sc0 = fzero16(), sc1 = fzero16();
#pragma unroll
    for (int c = 0; c < 4; ++c) {
      {
        int krow = l31;
        int byo = (c * 32 + hi * 16) ^ ((krow & 7) << 4);
        bf16x8 kf = *(const bf16x8*)(lk + krow * 128 + byo);
        sc0 = mfma32(kf, qf[c], sc0);
      }
      {
        int krow = 32 + l31;
        int byo = (c * 32 + hi * 16) ^ ((krow & 7) << 4);
        bf16x8 kf = *(const bf16x8*)(lk + krow * 128 + byo);
        sc1 = mfma32(kf, qf[c], sc1);
      }
    }

    // ---- mask: one u64 per lane (this lane's q row), bit = k - k0
    unsigned long long mw = Mb[q * 32 + it];
    uint mm0 = ((uint)mw) >> (4 * hi);
    uint mm1 = ((uint)(mw >> 32)) >> (4 * hi);
    float rm = -1e30f;
#pragma unroll
    for (int r = 0; r < 16; ++r) {
      const int bit = (r & 3) + 8 * (r >> 2);   // + 4*hi already shifted out
      float s0 = ((mm0 >> bit) & 1u) ? sc0[r] : -1e9f;
      float s1 = ((mm1 >> bit) & 1u) ? sc1[r] : -1e9f;
      sc0[r] = s0; sc1[r] = s1;
      rm = fmaxf(rm, fmaxf(s0, s1));
    }
    rm = fmaxf(rm, __shfl_xor(rm, 32));         // other hi half holds other k's
    float mn = fmaxf(m_r, rm);
    float corr = __expf(m_r - mn);
    m_r = mn;
    float rs = 0.f;
#pragma unroll
    for (int r = 0; r < 16; ++r) {
      float p0 = __expf(sc0[r] - mn);
      float p1 = __expf(sc1[r] - mn);
      sc0[r] = p0; sc1[r] = p1;
      rs += p0 + p1;
    }
    rs += __shfl_xor(rs, 32);
    l_r = l_r * corr + rs;
    xacc0 = xacc0 * corr;
    xacc1 = xacc1 * corr;

    // ---- pack P rows to bf16 pairs (adjacent k)
    uint cp0[8], cp1[8];
#pragma unroll
    for (int m = 0; m < 8; ++m) {
      cp0[m] = pk2(sc0[2 * m], sc0[2 * m + 1]);
      cp1[m] = pk2(sc1[2 * m], sc1[2 * m + 1]);
    }

    // ---- PV: per 16-k slice, permlane32_swap assembles the P B-fragment
#define PV_SLICE(CPK, S) do {                                               \
      uint w0 = CPK[4 * ((S) & 1) + 0], w2 = CPK[4 * ((S) & 1) + 2];        \
      uint w1 = CPK[4 * ((S) & 1) + 1], w3 = CPK[4 * ((S) & 1) + 3];        \
      asm volatile("v_permlane32_swap_b32 %0, %1" : "+v"(w0), "+v"(w2));    \
      asm volatile("v_permlane32_swap_b32 %0, %1" : "+v"(w1), "+v"(w3));    \
      union { uint u[4]; bf16x8 v8; } pu;                                   \
      pu.u[0] = w0; pu.u[1] = w1; pu.u[2] = w2; pu.u[3] = w3;               \
      { int vrow = l31;                                                     \
        int byo = ((S) * 32 + hi * 16) ^ ((vrow & 7) << 4);                 \
        bf16x8 vf = *(const bf16x8*)(lv + vrow * 128 + byo);                \
        xacc0 = mfma32(vf, pu.v8, xacc0); }                                 \
      { int vrow = 32 + l31;                                                \
        int byo = ((S) * 32 + hi * 16) ^ ((vrow & 7) << 4);                 \
        bf16x8 vf = *(const bf16x8*)(lv + vrow * 128 + byo);                \
        xacc1 = mfma32(vf, pu.v8, xacc1); }                                 \
    } while (0)
    PV_SLICE(cp0, 0); PV_SLICE(cp0, 1); PV_SLICE(cp1, 2); PV_SLICE(cp1, 3);
#undef PV_SLICE
    cur ^= 1;
  }

  // ---- finalize: X[d][q] * 1/l, store to Xb[b*2048+q][h*64+d]
  float inv = 1.f / l_r;
  __bf16* orow = Xb + (b * 2048 + q) * 1024 + h * 64 + 4 * hi;
#pragma unroll
  for (int g = 0; g < 4; ++g) {
    st4bf(orow + 8 * g,      xacc0[4 * g] * inv, xacc0[4 * g + 1] * inv,
                             xacc0[4 * g + 2] * inv, xacc0[4 * g + 3] * inv);
    st4bf(orow + 32 + 8 * g, xacc1[4 * g] * inv, xacc1[4 * g + 1] * inv,
                             xacc1[4 * g + 2] * inv, xacc1[4 * g + 3] * inv);
  }
}

// ---------------------------------------------------------------------------
extern "C" void kernel_launch(void* const* d_in, const int* in_sizes, int n_in,
                              void* d_out, int out_size, void* d_ws, size_t ws_size,
                              hipStream_t stream) {
  const float* q    = (const float*)d_in[0];
  const float* k    = (const float*)d_in[1];
  const float* v    = (const float*)d_in[2];
  const int*   mask = (const int*)d_in[3];
  const float* wq   = (const float*)d_in[4];
  const float* bq   = (const float*)d_in[5];
  const float* wk   = (const float*)d_in[6];
  const float* bk   = (const float*)d_in[7];
  const float* wv   = (const float*)d_in[8];
  const float* bv   = (const float*)d_in[9];
  const float* wo   = (const float*)d_in[10];
  const float* bo   = (const float*)d_in[11];

  char* ws = (char*)d_ws;
  // layout (bytes): Wb 8MB | Qp 16MB | Kp 16MB | Vt 16MB | Xb 16MB | Mb 0.5MB
  __bf16* Wb  = (__bf16*)(ws);
  __bf16* Qp  = (__bf16*)(ws + (size_t)(8u  << 20));
  __bf16* Kp  = (__bf16*)(ws + (size_t)(24u << 20));
  __bf16* Vtb = (__bf16*)(ws + (size_t)(40u << 20));
  __bf16* Xb  = (__bf16*)(ws + (size_t)(56u << 20));
  unsigned long long* Mb = (unsigned long long*)(ws + (size_t)(72u << 20));

  cvt_w<<<4096, 256, 0, stream>>>(wq, wk, wv, wo, Wb);
  pack_mask<<<1024, 256, 0, stream>>>(mask, Mb);
  gemm_bt<0><<<dim3(64, 8), 256, 0, stream>>>(q, Wb,                 bq, Qp);
  gemm_bt<1><<<dim3(64, 8), 256, 0, stream>>>(k, Wb + (1u << 20),    bk, Kp);
  gemm_bt<2><<<dim3(64, 8), 256, 0, stream>>>(v, Wb + (2u << 20),    bv, Vtb);
  attn_fwd<<<dim3(16, 64), 256, 0, stream>>>(Qp, Kp, Vtb, Mb, Xb);
  gemm_bt<3><<<dim3(64, 8), 256, 0, stream>>>(Xb, Wb + (3u << 20),   bo, (float*)d_out);
}

// Round 3
// 443.406 us; speedup vs baseline: 1.3195x; 1.0047x over previous
//
#include <hip/hip_runtime.h>

// ---------------------------------------------------------------------------
// MultiHeadAttentionBlock: B=4, S=2048, D=1024, H=16, DK=64
// cvt weights -> pack mask bits -> Q/K/V proj (bf16 MFMA GEMM, dbuf)
// -> flash attention (32x32 swapped-operand, exp2 softmax, defer-rescale)
// -> out proj
// ---------------------------------------------------------------------------

typedef __bf16  bf16x8 __attribute__((ext_vector_type(8)));
typedef float   f32x4  __attribute__((ext_vector_type(4)));
typedef float   f32x16 __attribute__((ext_vector_type(16)));
typedef float   fv4    __attribute__((ext_vector_type(4)));
typedef unsigned int uint;
typedef __attribute__((address_space(3))) char        as3c;
typedef __attribute__((address_space(1))) const char  as1c;

static __device__ __forceinline__ void gload16(const void* g, void* l) {
  __builtin_amdgcn_global_load_lds((as1c*)g, (as3c*)l, 16, 0, 0);
}
static __device__ __forceinline__ f32x4 mfma16(bf16x8 a, bf16x8 b, f32x4 c) {
  return __builtin_amdgcn_mfma_f32_16x16x32_bf16(a, b, c, 0, 0, 0);
}
static __device__ __forceinline__ f32x16 mfma32(bf16x8 a, bf16x8 b, f32x16 c) {
  return __builtin_amdgcn_mfma_f32_32x32x16_bf16(a, b, c, 0, 0, 0);
}
static __device__ __forceinline__ void st4bf(void* dst, float a, float b, float c, float d) {
  union { __bf16 h[4]; unsigned long long u; } x;
  x.h[0] = (__bf16)a; x.h[1] = (__bf16)b; x.h[2] = (__bf16)c; x.h[3] = (__bf16)d;
  *(unsigned long long*)dst = x.u;
}
static __device__ __forceinline__ uint pk2(float lo, float hi) {
  union { __bf16 h[2]; uint u; } x;
  x.h[0] = (__bf16)lo; x.h[1] = (__bf16)hi; return x.u;
}
static __device__ __forceinline__ f32x16 fzero16() {
  f32x16 z;
#pragma unroll
  for (int i = 0; i < 16; ++i) z[i] = 0.f;
  return z;
}

// ---- weights f32 -> bf16 (4 x 1M elements, exact grid) ----------------------
__global__ void cvt_w(const float* __restrict__ w0, const float* __restrict__ w1,
                      const float* __restrict__ w2, const float* __restrict__ w3,
                      __bf16* __restrict__ dst) {
  int i = (blockIdx.x * 256 + threadIdx.x) * 4;
  int seg = i >> 20, off = i & 1048575;
  const float* s = seg == 0 ? w0 : seg == 1 ? w1 : seg == 2 ? w2 : w3;
  fv4 v = *(const fv4*)(s + off);
  st4bf(dst + i, v[0], v[1], v[2], v[3]);
}

// ---- mask int32 [2048][2048] -> bit-packed u64 [2048][32] -------------------
__global__ void pack_mask(const int* __restrict__ mask,
                          unsigned long long* __restrict__ out) {
  int wid = threadIdx.x >> 6, lane = threadIdx.x & 63;
  for (int w = blockIdx.x * 4 + wid; w < 2048 * 32; w += gridDim.x * 4) {
    int v = mask[(w >> 5) * 2048 + (w & 31) * 64 + lane];
    unsigned long long bits = __ballot(v != 0);
    if (lane == 0) out[w] = bits;
  }
}

// ---- GEMM  C[M=8192][N=1024] = A[8192][1024] @ W[N][K]^T + bias -------------
// MODE 0: A=f32, out bf16, *(0.125*log2e) (Q)   MODE 1: A=f32, out bf16 (K)
// MODE 2: A=f32, out bf16 TRANSPOSED to Vt[b*1024+n][2048] (V)
// MODE 3: A=bf16, out f32 (final projection)
// Double-buffered: B (and A for MODE 3) via global_load_lds; A f32 reg-staged
// with loads issued after barrier2 so they fly across the compute phase.
template<int MODE>
__global__ __launch_bounds__(256, 2)
void gemm_bt(const void* __restrict__ Ap, const __bf16* __restrict__ Bw,
             const float* __restrict__ bias, void* __restrict__ Cp) {
  __shared__ __align__(16) char lds_a[2][8192];   // 128 rows x 32 k (bf16)
  __shared__ __align__(16) char lds_b[2][8192];
  const int t = threadIdx.x;
  const int lane = t & 63, lr = lane & 15, lg = lane >> 4;
  const int wid = t >> 6, wr = wid >> 1, wc = wid & 1;
  // XCD swizzle: 512 blocks, each XCD owns one 128-col B panel
  const int bid = blockIdx.x;
  const int nid = (bid & 7) * 64 + (bid >> 3);
  const int rowStart = (nid & 63) * 128, colStart = (nid >> 6) * 128;

  const float*  Af = (const float*)Ap;
  const __bf16* Ah = (const __bf16*)Ap;
  fv4 ra[4];

  auto loadA = [&](int kt) {            // issue A f32 loads into regs
    if constexpr (MODE < 3) {
#pragma unroll
      for (int rr = 0; rr < 4; ++rr) {
        int lin = rr * 1024 + t * 4;
        int row = lin >> 5, col = lin & 31;
        ra[rr] = *(const fv4*)(Af + (rowStart + row) * 1024 + kt + col);
      }
    }
  };
  auto writeA = [&](int buf) {          // convert + ds_write
    if constexpr (MODE < 3) {
#pragma unroll
      for (int rr = 0; rr < 4; ++rr) {
        int lin = rr * 1024 + t * 4;
        st4bf(&lds_a[buf][lin * 2], ra[rr][0], ra[rr][1], ra[rr][2], ra[rr][3]);
      }
    }
  };
  auto stageAB = [&](int buf, int kt) { // global_load_lds parts
    if constexpr (MODE == 3) {
#pragma unroll
      for (int rr = 0; rr < 2; ++rr) {
        int lin = rr * 2048 + t * 8;
        int row = lin >> 5, col = lin & 31;
        gload16(Ah + (rowStart + row) * 1024 + kt + col, &lds_a[buf][lin * 2]);
      }
    }
#pragma unroll
    for (int rr = 0; rr < 2; ++rr) {
      int lin = rr * 2048 + t * 8;
      int row = lin >> 5, col = lin & 31;
      gload16(Bw + (colStart + row) * 1024 + kt + col, &lds_b[buf][lin * 2]);
    }
  };

  f32x4 acc[4][4];
#pragma unroll
  for (int m = 0; m < 4; ++m)
#pragma unroll
    for (int n = 0; n < 4; ++n) {
      acc[m][n][0] = 0.f; acc[m][n][1] = 0.f; acc[m][n][2] = 0.f; acc[m][n][3] = 0.f;
    }

  loadA(0); stageAB(0, 0);
  int cur = 0;
  for (int it = 0; it < 32; ++it) {
    __syncthreads();                    // vmcnt(0): ra ready, B(it) in LDS
    if constexpr (MODE < 3) {
      writeA(cur);
      __syncthreads();                  // lgkm drain: A tile visible
    }
    if (it + 1 < 32) { loadA((it + 1) * 32); stageAB(cur ^ 1, (it + 1) * 32); }

    bf16x8 af[4], bfr[4];
#pragma unroll
    for (int m = 0; m < 4; ++m)
      af[m] = *(const bf16x8*)(&lds_a[cur][(wr * 64 + m * 16 + lr) * 64 + lg * 16]);
#pragma unroll
    for (int n = 0; n < 4; ++n)
      bfr[n] = *(const bf16x8*)(&lds_b[cur][(wc * 64 + n * 16 + lr) * 64 + lg * 16]);
#pragma unroll
    for (int m = 0; m < 4; ++m)
#pragma unroll
      for (int n = 0; n < 4; ++n)
        acc[m][n] = mfma16(af[m], bfr[n], acc[m][n]);
    cur ^= 1;
  }

  // epilogue: C/D layout row=(lane>>4)*4+r, col=lane&15
#pragma unroll
  for (int n = 0; n < 4; ++n) {
    int col = colStart + wc * 64 + n * 16 + lr;
    float bv = bias[col];
#pragma unroll
    for (int m = 0; m < 4; ++m) {
      int rowb = rowStart + wr * 64 + m * 16 + lg * 4;
      if constexpr (MODE == 0 || MODE == 1) {
        __bf16* C = (__bf16*)Cp;
#pragma unroll
        for (int r = 0; r < 4; ++r) {
          float val = acc[m][n][r] + bv;
          if constexpr (MODE == 0) val *= 0.18033688011112042f; // 1/8 * log2(e)
          C[(rowb + r) * 1024 + col] = (__bf16)val;
        }
      } else if constexpr (MODE == 2) {
        __bf16* C = (__bf16*)Cp;                     // Vt[b*1024+n][2048]
        int bb = rowb >> 11, s = rowb & 2047;        // rows are consecutive s
        st4bf(C + ((bb << 10) + col) * 2048 + s,
              acc[m][n][0] + bv, acc[m][n][1] + bv,
              acc[m][n][2] + bv, acc[m][n][3] + bv);
      } else {
        float* C = (float*)Cp;
#pragma unroll
        for (int r = 0; r < 4; ++r)
          C[(rowb + r) * 1024 + col] = acc[m][n][r] + bv;
      }
    }
  }
}

// ---- flash attention, 32x32 swapped-operand form ----------------------------
// 1024 blocks (XCD-swizzled), 256 thr. Wave owns 32 q (q = lane&31), KBLK=64.
// QK^T = mfma(K, Q) -> S[k][q];  PV = mfma(Vt, P) -> X[d][q].
// Softmax in exp2 domain (log2e folded into Q); unmasked max (exact);
// mask applied as sign-extend AND-zero on p; defer-rescale THR=8.
__global__ __launch_bounds__(256, 3)
void attn_fwd(const __bf16* __restrict__ Qp, const __bf16* __restrict__ Kp,
              const __bf16* __restrict__ Vt, const unsigned long long* __restrict__ Mb,
              __bf16* __restrict__ Xb) {
  __shared__ __align__(16) char lds[2][16384];   // [buf][ K:8192 | V:8192 ]
  const int t = threadIdx.x;
  const int lane = t & 63;
  const int l31 = lane & 31, hi = lane >> 5;
  const int wid = t >> 6;
  // XCD swizzle: 128 consecutive nids (8 full bh groups) per XCD
  const int bid = blockIdx.x;
  const int nid = (bid & 7) * 128 + (bid >> 3);
  const int qblk = nid & 15, bh = nid >> 4;
  const int b = bh >> 4, h = bh & 15;
  const int q = qblk * 128 + wid * 32 + l31;     // this lane's q column

  // Q fragments (B operand): row q, d = c*16 + hi*8 + j  (pre-scaled by log2e/8)
  bf16x8 qf[4];
#pragma unroll
  for (int c = 0; c < 4; ++c)
    qf[c] = *(const bf16x8*)(Qp + (b * 2048 + q) * 1024 + h * 64 + c * 16 + hi * 8);

  f32x16 xacc0 = fzero16(), xacc1 = fzero16();   // X[d][q], d-tiles 0..31 / 32..63
  float m_r = -1e30f, l_r = 0.f;

  // stage K and Vt tiles; LDS linear dest, XOR swizzle folded into global src
  auto stage = [&](int buf, int k0) {
#pragma unroll
    for (int rr = 0; rr < 2; ++rr) {
      int o = rr * 4096 + t * 16;
      int row = o >> 7, cb = o & 127;
      int cbs = cb ^ ((row & 7) << 4);
      gload16(Kp + (b * 2048 + k0 + row) * 1024 + h * 64 + (cbs >> 1), &lds[buf][o]);
      gload16(Vt + (bh * 64 + row) * 2048 + k0 + (cbs >> 1), &lds[buf][8192 + o]);
    }
  };

  stage(0, 0);
  int cur = 0;
  for (int it = 0; it < 32; ++it) {
    __syncthreads();                 // drains own gload_lds (vmcnt) + barrier
    if (it + 1 < 32) stage(cur ^ 1, (it + 1) * 64);   // overlap with compute

    const char* lk = lds[cur];
    const char* lv = lds[cur] + 8192;

    // ---- scores S[k][q] (2 k-tiles of 32), contraction d=64 in 4 slices
    f32x16 sc0 = fzero16(), sc1 = fzero16();
#pragma unroll
    for (int c = 0; c < 4; ++c) {
      {
        int krow = l31;
        int byo = (c * 32 + hi * 16) ^ ((krow & 7) << 4);
        bf16x8 kf = *(const bf16x8*)(lk + krow * 128 + byo);
        sc0 = mfma32(kf, qf[c], sc0);
      }
      {
        int krow = 32 + l31;
        int byo = (c * 32 + hi * 16) ^ ((krow & 7) << 4);
        bf16x8 kf = *(const bf16x8*)(lk + krow * 128 + byo);
        sc1 = mfma32(kf, qf[c], sc1);
      }
    }

    // ---- unmasked row max (exact: any m >= true max just rescales p and l)
    float rm = -1e30f;
#pragma unroll
    for (int r = 0; r < 16; ++r) rm = fmaxf(rm, fmaxf(sc0[r], sc1[r]));
    rm = fmaxf(rm, __shfl_xor(rm, 32));

    // ---- defer-rescale (THR=8 in exp2 domain)
    if (__any(rm > m_r + 8.f)) {
      float mn = fmaxf(m_r, rm);
      float corr = __builtin_amdgcn_exp2f(m_r - mn);
      m_r = mn;
      l_r *= corr;
      xacc0 = xacc0 * corr;
      xacc1 = xacc1 * corr;
    }

    // ---- p = exp2(s - m), mask via sign-extend AND-zero, row-sum
    unsigned long long mw = Mb[q * 32 + it];
    uint mm0 = ((uint)mw) >> (4 * hi);
    uint mm1 = ((uint)(mw >> 32)) >> (4 * hi);
    float rs = 0.f;
#pragma unroll
    for (int r = 0; r < 16; ++r) {
      const int bit = (r & 3) + 8 * (r >> 2);
      float p0 = __builtin_amdgcn_exp2f(sc0[r] - m_r);
      float p1 = __builtin_amdgcn_exp2f(sc1[r] - m_r);
      uint z0 = (uint)((int)(mm0 << (31 - bit)) >> 31);
      uint z1 = (uint)((int)(mm1 << (31 - bit)) >> 31);
      p0 = __uint_as_float(__float_as_uint(p0) & z0);
      p1 = __uint_as_float(__float_as_uint(p1) & z1);
      sc0[r] = p0; sc1[r] = p1;
      rs += p0 + p1;
    }
    rs += __shfl_xor(rs, 32);
    l_r += rs;

    // ---- pack P rows to bf16 pairs (adjacent k)
    uint cp0[8], cp1[8];
#pragma unroll
    for (int m = 0; m < 8; ++m) {
      cp0[m] = pk2(sc0[2 * m], sc0[2 * m + 1]);
      cp1[m] = pk2(sc1[2 * m], sc1[2 * m + 1]);
    }

    // ---- PV: per 16-k slice, permlane32_swap assembles the P B-fragment
#define PV_SLICE(CPK, S) do {                                               \
      uint w0 = CPK[4 * ((S) & 1) + 0], w2 = CPK[4 * ((S) & 1) + 2];        \
      uint w1 = CPK[4 * ((S) & 1) + 1], w3 = CPK[4 * ((S) & 1) + 3];        \
      asm volatile("v_permlane32_swap_b32 %0, %1" : "+v"(w0), "+v"(w2));    \
      asm volatile("v_permlane32_swap_b32 %0, %1" : "+v"(w1), "+v"(w3));    \
      union { uint u[4]; bf16x8 v8; } pu;                                   \
      pu.u[0] = w0; pu.u[1] = w1; pu.u[2] = w2; pu.u[3] = w3;               \
      { int vrow = l31;                                                     \
        int byo = (((S) * 32 + hi * 16)) ^ ((vrow & 7) << 4);               \
        bf16x8 vf = *(const bf16x8*)(lv + vrow * 128 + byo);                \
        xacc0 = mfma32(vf, pu.v8, xacc0); }                                 \
      { int vrow = 32 + l31;                                                \
        int byo = (((S) * 32 + hi * 16)) ^ ((vrow & 7) << 4);               \
        bf16x8 vf = *(const bf16x8*)(lv + vrow * 128 + byo);                \
        xacc1 = mfma32(vf, pu.v8, xacc1); }                                 \
    } while (0)
    PV_SLICE(cp0, 0); PV_SLICE(cp0, 1); PV_SLICE(cp1, 2); PV_SLICE(cp1, 3);
#undef PV_SLICE
    cur ^= 1;
  }

  // ---- finalize: X[d][q] * 1/l, store to Xb[b*2048+q][h*64+d]
  float inv = 1.f / l_r;
  __bf16* orow = Xb + (b * 2048 + q) * 1024 + h * 64 + 4 * hi;
#pragma unroll
  for (int g = 0; g < 4; ++g) {
    st4bf(orow + 8 * g,      xacc0[4 * g] * inv, xacc0[4 * g + 1] * inv,
                             xacc0[4 * g + 2] * inv, xacc0[4 * g + 3] * inv);
    st4bf(orow + 32 + 8 * g, xacc1[4 * g] * inv, xacc1[4 * g + 1] * inv,
                             xacc1[4 * g + 2] * inv, xacc1[4 * g + 3] * inv);
  }
}

// ---------------------------------------------------------------------------
extern "C" void kernel_launch(void* const* d_in, const int* in_sizes, int n_in,
                              void* d_out, int out_size, void* d_ws, size_t ws_size,
                              hipStream_t stream) {
  const float* q    = (const float*)d_in[0];
  const float* k    = (const float*)d_in[1];
  const float* v    = (const float*)d_in[2];
  const int*   mask = (const int*)d_in[3];
  const float* wq   = (const float*)d_in[4];
  const float* bq   = (const float*)d_in[5];
  const float* wk   = (const float*)d_in[6];
  const float* bk   = (const float*)d_in[7];
  const float* wv   = (const float*)d_in[8];
  const float* bv   = (const float*)d_in[9];
  const float* wo   = (const float*)d_in[10];
  const float* bo   = (const float*)d_in[11];

  char* ws = (char*)d_ws;
  // layout (bytes): Wb 8MB | Qp 16MB | Kp 16MB | Vt 16MB | Xb 16MB | Mb 0.5MB
  __bf16* Wb  = (__bf16*)(ws);
  __bf16* Qp  = (__bf16*)(ws + (size_t)(8u  << 20));
  __bf16* Kp  = (__bf16*)(ws + (size_t)(24u << 20));
  __bf16* Vtb = (__bf16*)(ws + (size_t)(40u << 20));
  __bf16* Xb  = (__bf16*)(ws + (size_t)(56u << 20));
  unsigned long long* Mb = (unsigned long long*)(ws + (size_t)(72u << 20));

  cvt_w<<<4096, 256, 0, stream>>>(wq, wk, wv, wo, Wb);
  pack_mask<<<1024, 256, 0, stream>>>(mask, Mb);
  gemm_bt<0><<<512, 256, 0, stream>>>(q, Wb,              bq, Qp);
  gemm_bt<1><<<512, 256, 0, stream>>>(k, Wb + (1u << 20), bk, Kp);
  gemm_bt<2><<<512, 256, 0, stream>>>(v, Wb + (2u << 20), bv, Vtb);
  attn_fwd<<<1024, 256, 0, stream>>>(Qp, Kp, Vtb, Mb, Xb);
  gemm_bt<3><<<512, 256, 0, stream>>>(Xb, Wb + (3u << 20), bo, (float*)d_out);
}